// Round 2
// baseline (36909.683 us; speedup 1.0000x reference)
//
#include <hip/hip_runtime.h>
#include <hip/hip_cooperative_groups.h>

namespace cg = cooperative_groups;

#define B_ 256
#define T_ 512
#define I_ 128
#define H_ 256
#define C_ 1000

__device__ __forceinline__ float fsig(float x) { return 1.0f / (1.0f + __expf(-x)); }
__device__ __forceinline__ float ftanh(float x) { return 2.0f / (1.0f + __expf(-2.0f * x)) - 1.0f; }

// ---------------------------------------------------------------------------
// Persistent cooperative kernel: the per-step body is VERBATIM the proven
// 7506us lstm_step (transposed LDS [k][36], scalar staging, outer-product
// inner loop, LDS cross-wave reduce). Kernel boundaries between timesteps are
// replaced by one grid.sync() per step.
// wgs [0,256): layer 0 at t=s.  wgs [256,512): layer 1 at t=s-1.
// ---------------------------------------------------------------------------
__global__ __launch_bounds__(256) void lstm_persist(
    const float* __restrict__ x,
    const float* __restrict__ Wih0, const float* __restrict__ Whh0,
    const float* __restrict__ bih0, const float* __restrict__ bhh0,
    const float* __restrict__ Wih1, const float* __restrict__ Whh1,
    const float* __restrict__ bih1, const float* __restrict__ bhh1,
    float* __restrict__ ws)
{
    cg::grid_group grid = cg::this_grid();

    __shared__ float As[128 * 36];
    __shared__ float Wsh[128 * 36];

    float* h0buf = ws;                 // [2][B*H]
    float* h1buf = ws + 2 * B_ * H_;   // [2][B*H]
    float* c0 = ws + 4 * B_ * H_;
    float* c1 = ws + 5 * B_ * H_;

    const int w = blockIdx.x;
    const int layer = w >> 8;
    const int r = w & 255;
    const int bb = r >> 5;   // batch block (8 of 32)
    const int hb = r & 31;   // h block (32 of 8 h-indices -> 32 gate rows)

    const int tid = threadIdx.x;
    const int srow = tid >> 3;   // staging row 0..31
    const int kv = tid & 7;      // staging k-vector lane
    const int wave = tid >> 6;
    const int lane = tid & 63;
    const int br = lane >> 3;    // batch quad 0..7
    const int gc8 = lane & 7;    // gate quad 0..7
    const int grow = (srow >> 3) * H_ + hb * 8 + (srow & 7);

    // layer-invariant bindings (hoisted out of the step loop)
    const float* Wih; const float* Whh; const float* bi; const float* bh;
    float* cbuf; int nchunks;
    if (layer == 0) { Wih = Wih0; Whh = Whh0; bi = bih0; bh = bhh0; cbuf = c0; nchunks = 3; }
    else            { Wih = Wih1; Whh = Whh1; bi = bih1; bh = bhh1; cbuf = c1; nchunks = 4; }

    for (int s = 0; s <= T_; ++s) {
        const bool active = (layer == 0) ? (s < T_) : (s >= 1);
        if (active) {
            const int t = (layer == 0) ? s : (s - 1);
            const float* hprev; const float* h0cur = nullptr; float* hout;
            if (layer == 0) {
                hprev = h0buf + ((t - 1) & 1) * B_ * H_;
                hout  = h0buf + (t & 1) * B_ * H_;
            } else {
                h0cur = h0buf + (t & 1) * B_ * H_;
                hprev = h1buf + ((t - 1) & 1) * B_ * H_;
                hout  = h1buf + (t & 1) * B_ * H_;
            }

            float acc[4][4];
#pragma unroll
            for (int a = 0; a < 4; ++a)
#pragma unroll
                for (int b = 0; b < 4; ++b) acc[a][b] = 0.0f;

            for (int cc = 0; cc < nchunks; ++cc) {
                const float* ap;
                const float* wp;
                if (layer == 0) {
                    if (cc == 0) { ap = x + ((size_t)(bb * 32 + srow) * T_ + t) * I_; wp = Wih + grow * I_; }
                    else         { ap = hprev + (bb * 32 + srow) * H_ + (cc - 1) * 128; wp = Whh + grow * H_ + (cc - 1) * 128; }
                } else {
                    if (cc < 2)  { ap = h0cur + (bb * 32 + srow) * H_ + cc * 128;       wp = Wih + grow * H_ + cc * 128; }
                    else         { ap = hprev + (bb * 32 + srow) * H_ + (cc - 2) * 128; wp = Whh + grow * H_ + (cc - 2) * 128; }
                }
#pragma unroll
                for (int i = 0; i < 4; ++i) {
                    const int k4 = (kv + 8 * i) * 4;
                    float4 va = *(const float4*)(ap + k4);
                    As[(k4 + 0) * 36 + srow] = va.x;
                    As[(k4 + 1) * 36 + srow] = va.y;
                    As[(k4 + 2) * 36 + srow] = va.z;
                    As[(k4 + 3) * 36 + srow] = va.w;
                    float4 vw = *(const float4*)(wp + k4);
                    Wsh[(k4 + 0) * 36 + srow] = vw.x;
                    Wsh[(k4 + 1) * 36 + srow] = vw.y;
                    Wsh[(k4 + 2) * 36 + srow] = vw.z;
                    Wsh[(k4 + 3) * 36 + srow] = vw.w;
                }
                __syncthreads();
                const float* Ap = &As[(wave * 32) * 36 + br * 4];
                const float* Wp = &Wsh[(wave * 32) * 36 + gc8 * 4];
#pragma unroll
                for (int kk = 0; kk < 32; ++kk) {
                    float4 a = *(const float4*)(Ap + kk * 36);
                    float4 wv = *(const float4*)(Wp + kk * 36);
                    acc[0][0] += a.x * wv.x; acc[0][1] += a.x * wv.y; acc[0][2] += a.x * wv.z; acc[0][3] += a.x * wv.w;
                    acc[1][0] += a.y * wv.x; acc[1][1] += a.y * wv.y; acc[1][2] += a.y * wv.z; acc[1][3] += a.y * wv.w;
                    acc[2][0] += a.z * wv.x; acc[2][1] += a.z * wv.y; acc[2][2] += a.z * wv.z; acc[2][3] += a.z * wv.w;
                    acc[3][0] += a.w * wv.x; acc[3][1] += a.w * wv.y; acc[3][2] += a.w * wv.z; acc[3][3] += a.w * wv.w;
                }
                __syncthreads();
            }

            // cross-wave reduction via LDS (reuse As)
            float* red = As;
            {
                const int base = tid * 16;
#pragma unroll
                for (int a = 0; a < 4; ++a)
#pragma unroll
                    for (int b = 0; b < 4; ++b)
                        red[base + a * 4 + b] = acc[a][b];
            }
            __syncthreads();
            {
                const int bl = tid >> 3;  // local batch 0..31
                const int j = tid & 7;    // local h-index 0..7
                float g4[4];
#pragma unroll
                for (int g = 0; g < 4; ++g) {
                    const int gc = g * 8 + j;
                    const int br2 = bl >> 2, bi2 = bl & 3, gq = gc >> 2, gj = gc & 3;
                    float v = 0.0f;
#pragma unroll
                    for (int wv = 0; wv < 4; ++wv)
                        v += red[(wv * 64 + br2 * 8 + gq) * 16 + bi2 * 4 + gj];
                    const int growg = g * H_ + hb * 8 + j;
                    v += bi[growg] + bh[growg];
                    g4[g] = v;
                }
                const float ig = fsig(g4[0]);
                const float fg = fsig(g4[1]);
                const float gg = ftanh(g4[2]);
                const float og = fsig(g4[3]);
                const int b = bb * 32 + bl;
                const int hidx = hb * 8 + j;
                const int ci = b * H_ + hidx;
                const float cn = fg * cbuf[ci] + ig * gg;
                cbuf[ci] = cn;
                hout[ci] = og * ftanh(cn);
            }
        }
        grid.sync();
    }
}

// ---------------------------------------------------------------------------
// Fallback per-step kernel (proven 7506us version, verbatim) — used only if
// cooperative launch is unavailable.
// ---------------------------------------------------------------------------
__global__ __launch_bounds__(256) void lstm_step(
    const float* __restrict__ x,
    const float* __restrict__ Wih0, const float* __restrict__ Whh0,
    const float* __restrict__ bih0, const float* __restrict__ bhh0,
    const float* __restrict__ Wih1, const float* __restrict__ Whh1,
    const float* __restrict__ bih1, const float* __restrict__ bhh1,
    float* __restrict__ ws, int s)
{
    __shared__ float As[128 * 36];
    __shared__ float Wsh[128 * 36];

    float* h0buf = ws;
    float* h1buf = ws + 2 * B_ * H_;
    float* c0 = ws + 4 * B_ * H_;
    float* c1 = ws + 5 * B_ * H_;

    const int w = blockIdx.x;
    const int layer = w >> 8;
    const int r = w & 255;
    const int bb = r >> 5;
    const int hb = r & 31;

    if (layer == 0 && s >= T_) return;
    if (layer == 1 && s < 1) return;
    const int t = (layer == 0) ? s : (s - 1);

    const float* hprev; const float* h0cur = nullptr;
    float* hout; float* cbuf;
    const float* Wih; const float* Whh; const float* bi; const float* bh;
    int nchunks;
    if (layer == 0) {
        hprev = h0buf + ((t - 1) & 1) * B_ * H_;
        hout  = h0buf + (t & 1) * B_ * H_;
        cbuf = c0; Wih = Wih0; Whh = Whh0; bi = bih0; bh = bhh0;
        nchunks = 3;
    } else {
        h0cur = h0buf + (t & 1) * B_ * H_;
        hprev = h1buf + ((t - 1) & 1) * B_ * H_;
        hout  = h1buf + (t & 1) * B_ * H_;
        cbuf = c1; Wih = Wih1; Whh = Whh1; bi = bih1; bh = bhh1;
        nchunks = 4;
    }

    const int tid = threadIdx.x;
    const int srow = tid >> 3;
    const int kv = tid & 7;
    const int wave = tid >> 6;
    const int lane = tid & 63;
    const int br = lane >> 3;
    const int gc8 = lane & 7;
    const int grow = (srow >> 3) * H_ + hb * 8 + (srow & 7);

    float acc[4][4];
#pragma unroll
    for (int a = 0; a < 4; ++a)
#pragma unroll
        for (int b = 0; b < 4; ++b) acc[a][b] = 0.0f;

    for (int cc = 0; cc < nchunks; ++cc) {
        const float* ap;
        const float* wp;
        if (layer == 0) {
            if (cc == 0) { ap = x + ((size_t)(bb * 32 + srow) * T_ + t) * I_; wp = Wih + grow * I_; }
            else         { ap = hprev + (bb * 32 + srow) * H_ + (cc - 1) * 128; wp = Whh + grow * H_ + (cc - 1) * 128; }
        } else {
            if (cc < 2)  { ap = h0cur + (bb * 32 + srow) * H_ + cc * 128;       wp = Wih + grow * H_ + cc * 128; }
            else         { ap = hprev + (bb * 32 + srow) * H_ + (cc - 2) * 128; wp = Whh + grow * H_ + (cc - 2) * 128; }
        }
#pragma unroll
        for (int i = 0; i < 4; ++i) {
            const int k4 = (kv + 8 * i) * 4;
            float4 va = *(const float4*)(ap + k4);
            As[(k4 + 0) * 36 + srow] = va.x;
            As[(k4 + 1) * 36 + srow] = va.y;
            As[(k4 + 2) * 36 + srow] = va.z;
            As[(k4 + 3) * 36 + srow] = va.w;
            float4 vw = *(const float4*)(wp + k4);
            Wsh[(k4 + 0) * 36 + srow] = vw.x;
            Wsh[(k4 + 1) * 36 + srow] = vw.y;
            Wsh[(k4 + 2) * 36 + srow] = vw.z;
            Wsh[(k4 + 3) * 36 + srow] = vw.w;
        }
        __syncthreads();
        const float* Ap = &As[(wave * 32) * 36 + br * 4];
        const float* Wp = &Wsh[(wave * 32) * 36 + gc8 * 4];
#pragma unroll
        for (int kk = 0; kk < 32; ++kk) {
            float4 a = *(const float4*)(Ap + kk * 36);
            float4 wv = *(const float4*)(Wp + kk * 36);
            acc[0][0] += a.x * wv.x; acc[0][1] += a.x * wv.y; acc[0][2] += a.x * wv.z; acc[0][3] += a.x * wv.w;
            acc[1][0] += a.y * wv.x; acc[1][1] += a.y * wv.y; acc[1][2] += a.y * wv.z; acc[1][3] += a.y * wv.w;
            acc[2][0] += a.z * wv.x; acc[2][1] += a.z * wv.y; acc[2][2] += a.z * wv.z; acc[2][3] += a.z * wv.w;
            acc[3][0] += a.w * wv.x; acc[3][1] += a.w * wv.y; acc[3][2] += a.w * wv.z; acc[3][3] += a.w * wv.w;
        }
        __syncthreads();
    }

    float* red = As;
    {
        const int base = tid * 16;
#pragma unroll
        for (int a = 0; a < 4; ++a)
#pragma unroll
            for (int b = 0; b < 4; ++b)
                red[base + a * 4 + b] = acc[a][b];
    }
    __syncthreads();
    {
        const int bl = tid >> 3;
        const int j = tid & 7;
        float g4[4];
#pragma unroll
        for (int g = 0; g < 4; ++g) {
            const int gc = g * 8 + j;
            const int br2 = bl >> 2, bi2 = bl & 3, gq = gc >> 2, gj = gc & 3;
            float v = 0.0f;
#pragma unroll
            for (int wv = 0; wv < 4; ++wv)
                v += red[(wv * 64 + br2 * 8 + gq) * 16 + bi2 * 4 + gj];
            const int growg = g * H_ + hb * 8 + j;
            v += bi[growg] + bh[growg];
            g4[g] = v;
        }
        const float ig = fsig(g4[0]);
        const float fg = fsig(g4[1]);
        const float gg = ftanh(g4[2]);
        const float og = fsig(g4[3]);
        const int b = bb * 32 + bl;
        const int hidx = hb * 8 + j;
        const int ci = b * H_ + hidx;
        const float cn = fg * cbuf[ci] + ig * gg;
        cbuf[ci] = cn;
        hout[ci] = og * ftanh(cn);
    }
}

// out[b][c] = h1_final[b,:] . fcW[c,:] + fcb[c]; tiles [32 b x 32 c]
__global__ __launch_bounds__(256) void fc_kernel(
    const float* __restrict__ ws, const float* __restrict__ fcW,
    const float* __restrict__ fcb, float* __restrict__ out)
{
    __shared__ float As[128 * 36];
    __shared__ float Wsh[128 * 36];

    const float* h1 = ws + 3 * B_ * H_;  // h1buf[(T-1)&1] = h1buf[1]
    const int bb = blockIdx.x >> 5;
    const int cb = blockIdx.x & 31;
    const int tid = threadIdx.x;
    const int srow = tid >> 3;
    const int kv = tid & 7;
    const int wave = tid >> 6;
    const int lane = tid & 63;
    const int br = lane >> 3;
    const int gc8 = lane & 7;
    const int crow = cb * 32 + srow;

    float acc[4][4];
#pragma unroll
    for (int a = 0; a < 4; ++a)
#pragma unroll
        for (int b = 0; b < 4; ++b) acc[a][b] = 0.0f;

    for (int cc = 0; cc < 2; ++cc) {
        const float* ap = h1 + (bb * 32 + srow) * H_ + cc * 128;
#pragma unroll
        for (int i = 0; i < 4; ++i) {
            const int k4 = (kv + 8 * i) * 4;
            float4 va = *(const float4*)(ap + k4);
            As[(k4 + 0) * 36 + srow] = va.x;
            As[(k4 + 1) * 36 + srow] = va.y;
            As[(k4 + 2) * 36 + srow] = va.z;
            As[(k4 + 3) * 36 + srow] = va.w;
            float4 vw = make_float4(0.f, 0.f, 0.f, 0.f);
            if (crow < C_) vw = *(const float4*)(fcW + crow * H_ + cc * 128 + k4);
            Wsh[(k4 + 0) * 36 + srow] = vw.x;
            Wsh[(k4 + 1) * 36 + srow] = vw.y;
            Wsh[(k4 + 2) * 36 + srow] = vw.z;
            Wsh[(k4 + 3) * 36 + srow] = vw.w;
        }
        __syncthreads();
        const float* Ap = &As[(wave * 32) * 36 + br * 4];
        const float* Wp = &Wsh[(wave * 32) * 36 + gc8 * 4];
#pragma unroll
        for (int kk = 0; kk < 32; ++kk) {
            float4 a = *(const float4*)(Ap + kk * 36);
            float4 wv = *(const float4*)(Wp + kk * 36);
            acc[0][0] += a.x * wv.x; acc[0][1] += a.x * wv.y; acc[0][2] += a.x * wv.z; acc[0][3] += a.x * wv.w;
            acc[1][0] += a.y * wv.x; acc[1][1] += a.y * wv.y; acc[1][2] += a.y * wv.z; acc[1][3] += a.y * wv.w;
            acc[2][0] += a.z * wv.x; acc[2][1] += a.z * wv.y; acc[2][2] += a.z * wv.z; acc[2][3] += a.z * wv.w;
            acc[3][0] += a.w * wv.x; acc[3][1] += a.w * wv.y; acc[3][2] += a.w * wv.z; acc[3][3] += a.w * wv.w;
        }
        __syncthreads();
    }

    float* red = As;
    {
        const int base = tid * 16;
#pragma unroll
        for (int a = 0; a < 4; ++a)
#pragma unroll
            for (int b = 0; b < 4; ++b)
                red[base + a * 4 + b] = acc[a][b];
    }
    __syncthreads();
    {
        const int bl = tid >> 3;
        const int j = tid & 7;
#pragma unroll
        for (int g = 0; g < 4; ++g) {
            const int gc = g * 8 + j;
            const int br2 = bl >> 2, bi2 = bl & 3, gq = gc >> 2, gj = gc & 3;
            float v = 0.0f;
#pragma unroll
            for (int wv = 0; wv < 4; ++wv)
                v += red[(wv * 64 + br2 * 8 + gq) * 16 + bi2 * 4 + gj];
            const int cglob = cb * 32 + gc;
            if (cglob < C_) {
                v += fcb[cglob];
                out[(size_t)(bb * 32 + bl) * C_ + cglob] = v;
            }
        }
    }
}

extern "C" void kernel_launch(void* const* d_in, const int* in_sizes, int n_in,
                              void* d_out, int out_size, void* d_ws, size_t ws_size,
                              hipStream_t stream)
{
    const float* x    = (const float*)d_in[0];
    const float* Wih0 = (const float*)d_in[1];
    const float* Whh0 = (const float*)d_in[2];
    const float* bih0 = (const float*)d_in[3];
    const float* bhh0 = (const float*)d_in[4];
    const float* Wih1 = (const float*)d_in[5];
    const float* Whh1 = (const float*)d_in[6];
    const float* bih1 = (const float*)d_in[7];
    const float* bhh1 = (const float*)d_in[8];
    const float* fcW  = (const float*)d_in[9];
    const float* fcb  = (const float*)d_in[10];
    float* ws  = (float*)d_ws;
    float* out = (float*)d_out;

    // zero h0[2], h1[2], c0, c1 (ws is re-poisoned before every call)
    hipMemsetAsync(d_ws, 0, (size_t)6 * B_ * H_ * sizeof(float), stream);

    // persistent cooperative kernel: one grid.sync() per timestep instead of
    // 513 dependent kernel launches
    void* args[] = {
        (void*)&x,
        (void*)&Wih0, (void*)&Whh0, (void*)&bih0, (void*)&bhh0,
        (void*)&Wih1, (void*)&Whh1, (void*)&bih1, (void*)&bhh1,
        (void*)&ws
    };
    hipError_t err = hipLaunchCooperativeKernel(
        reinterpret_cast<void*>(lstm_persist), dim3(512), dim3(256),
        args, 0, stream);

    if (err != hipSuccess) {
        // fallback: proven per-step launch pipeline
        for (int s = 0; s <= T_; ++s) {
            lstm_step<<<512, 256, 0, stream>>>(x, Wih0, Whh0, bih0, bhh0,
                                               Wih1, Whh1, bih1, bhh1, ws, s);
        }
    }

    fc_kernel<<<256, 256, 0, stream>>>(ws, fcW, fcb, out);
}

// Round 3
// 7472.471 us; speedup vs baseline: 4.9394x; 4.9394x over previous
//
#include <hip/hip_runtime.h>

#define B_ 256
#define T_ 512
#define I_ 128
#define H_ 256
#define C_ 1000

#define RSTR 17   // reduction row stride (floats): coprime to 32 banks

__device__ __forceinline__ float fsig(float x) { return 1.0f / (1.0f + __expf(-x)); }
__device__ __forceinline__ float ftanh(float x) { return 2.0f / (1.0f + __expf(-2.0f * x)) - 1.0f; }

// Per-step kernel: wgs [0,256) do layer-0 at t=s; wgs [256,512) do layer-1 at t=s-1.
// Each wg: [32 batches x 32 gate-rows] tile, K chunked by 128 through LDS,
// K split across the 4 waves (4x4 register blocking), LDS reduce, activations.
// Identical to the proven 7506us kernel except the reduction stride 16 -> 17
// (kills the 32-way bank conflicts in the epilogue; FP order unchanged).
__global__ __launch_bounds__(256) void lstm_step(
    const float* __restrict__ x,
    const float* __restrict__ Wih0, const float* __restrict__ Whh0,
    const float* __restrict__ bih0, const float* __restrict__ bhh0,
    const float* __restrict__ Wih1, const float* __restrict__ Whh1,
    const float* __restrict__ bih1, const float* __restrict__ bhh1,
    float* __restrict__ ws, int s)
{
    __shared__ float As[128 * 36];
    __shared__ float Wsh[128 * 36];

    float* h0buf = ws;                 // [2][B*H]
    float* h1buf = ws + 2 * B_ * H_;   // [2][B*H]
    float* c0 = ws + 4 * B_ * H_;
    float* c1 = ws + 5 * B_ * H_;

    const int w = blockIdx.x;
    const int layer = w >> 8;
    const int r = w & 255;
    const int bb = r >> 5;   // batch block (8 of 32)
    const int hb = r & 31;   // h block (32 of 8 h-indices -> 32 gate rows)

    if (layer == 0 && s >= T_) return;
    if (layer == 1 && s < 1) return;
    const int t = (layer == 0) ? s : (s - 1);

    const float* hprev; const float* h0cur = nullptr;
    float* hout; float* cbuf;
    const float* Wih; const float* Whh; const float* bi; const float* bh;
    int nchunks;
    if (layer == 0) {
        hprev = h0buf + ((t - 1) & 1) * B_ * H_;
        hout  = h0buf + (t & 1) * B_ * H_;
        cbuf = c0; Wih = Wih0; Whh = Whh0; bi = bih0; bh = bhh0;
        nchunks = 3;   // K = 128 (x) + 256 (h0prev)
    } else {
        h0cur = h0buf + (t & 1) * B_ * H_;
        hprev = h1buf + ((t - 1) & 1) * B_ * H_;
        hout  = h1buf + (t & 1) * B_ * H_;
        cbuf = c1; Wih = Wih1; Whh = Whh1; bi = bih1; bh = bhh1;
        nchunks = 4;   // K = 256 (h0cur) + 256 (h1prev)
    }

    const int tid = threadIdx.x;
    const int srow = tid >> 3;   // staging row 0..31
    const int kv = tid & 7;      // staging k-vector lane
    const int wave = tid >> 6;
    const int lane = tid & 63;
    const int br = lane >> 3;    // batch quad 0..7
    const int gc8 = lane & 7;    // gate quad 0..7
    // global gate row for staging-row srow: gate (srow/8), h-index hb*8 + srow%8
    const int grow = (srow >> 3) * H_ + hb * 8 + (srow & 7);

    float acc[4][4];
#pragma unroll
    for (int a = 0; a < 4; ++a)
#pragma unroll
        for (int b = 0; b < 4; ++b) acc[a][b] = 0.0f;

    for (int cc = 0; cc < nchunks; ++cc) {
        const float* ap;
        const float* wp;
        if (layer == 0) {
            if (cc == 0) { ap = x + ((size_t)(bb * 32 + srow) * T_ + t) * I_; wp = Wih + grow * I_; }
            else         { ap = hprev + (bb * 32 + srow) * H_ + (cc - 1) * 128; wp = Whh + grow * H_ + (cc - 1) * 128; }
        } else {
            if (cc < 2)  { ap = h0cur + (bb * 32 + srow) * H_ + cc * 128;       wp = Wih + grow * H_ + cc * 128; }
            else         { ap = hprev + (bb * 32 + srow) * H_ + (cc - 2) * 128; wp = Whh + grow * H_ + (cc - 2) * 128; }
        }
#pragma unroll
        for (int i = 0; i < 4; ++i) {
            const int k4 = (kv + 8 * i) * 4;
            float4 va = *(const float4*)(ap + k4);
            As[(k4 + 0) * 36 + srow] = va.x;
            As[(k4 + 1) * 36 + srow] = va.y;
            As[(k4 + 2) * 36 + srow] = va.z;
            As[(k4 + 3) * 36 + srow] = va.w;
            float4 vw = *(const float4*)(wp + k4);
            Wsh[(k4 + 0) * 36 + srow] = vw.x;
            Wsh[(k4 + 1) * 36 + srow] = vw.y;
            Wsh[(k4 + 2) * 36 + srow] = vw.z;
            Wsh[(k4 + 3) * 36 + srow] = vw.w;
        }
        __syncthreads();
        const float* Ap = &As[(wave * 32) * 36 + br * 4];
        const float* Wp = &Wsh[(wave * 32) * 36 + gc8 * 4];
#pragma unroll
        for (int kk = 0; kk < 32; ++kk) {
            float4 a = *(const float4*)(Ap + kk * 36);
            float4 wv = *(const float4*)(Wp + kk * 36);
            acc[0][0] += a.x * wv.x; acc[0][1] += a.x * wv.y; acc[0][2] += a.x * wv.z; acc[0][3] += a.x * wv.w;
            acc[1][0] += a.y * wv.x; acc[1][1] += a.y * wv.y; acc[1][2] += a.y * wv.z; acc[1][3] += a.y * wv.w;
            acc[2][0] += a.z * wv.x; acc[2][1] += a.z * wv.y; acc[2][2] += a.z * wv.z; acc[2][3] += a.z * wv.w;
            acc[3][0] += a.w * wv.x; acc[3][1] += a.w * wv.y; acc[3][2] += a.w * wv.z; acc[3][3] += a.w * wv.w;
        }
        __syncthreads();
    }

    // cross-wave reduction via LDS (reuse As); stride 17 avoids bank conflicts
    float* red = As;
    {
        const int base = tid * RSTR;
#pragma unroll
        for (int a = 0; a < 4; ++a)
#pragma unroll
            for (int b = 0; b < 4; ++b)
                red[base + a * 4 + b] = acc[a][b];
    }
    __syncthreads();
    {
        const int bl = tid >> 3;  // local batch 0..31
        const int j = tid & 7;    // local h-index 0..7
        float g4[4];
#pragma unroll
        for (int g = 0; g < 4; ++g) {
            const int gc = g * 8 + j;
            const int br2 = bl >> 2, bi2 = bl & 3, gq = gc >> 2, gj = gc & 3;
            float v = 0.0f;
#pragma unroll
            for (int wv = 0; wv < 4; ++wv)
                v += red[(wv * 64 + br2 * 8 + gq) * RSTR + bi2 * 4 + gj];
            const int growg = g * H_ + hb * 8 + j;
            v += bi[growg] + bh[growg];
            g4[g] = v;
        }
        const float ig = fsig(g4[0]);
        const float fg = fsig(g4[1]);
        const float gg = ftanh(g4[2]);
        const float og = fsig(g4[3]);
        const int b = bb * 32 + bl;
        const int hidx = hb * 8 + j;
        const int ci = b * H_ + hidx;
        const float cn = fg * cbuf[ci] + ig * gg;
        cbuf[ci] = cn;
        hout[ci] = og * ftanh(cn);
    }
}

// out[b][c] = h1_final[b,:] . fcW[c,:] + fcb[c]; tiles [32 b x 32 c]
__global__ __launch_bounds__(256) void fc_kernel(
    const float* __restrict__ ws, const float* __restrict__ fcW,
    const float* __restrict__ fcb, float* __restrict__ out)
{
    __shared__ float As[128 * 36];
    __shared__ float Wsh[128 * 36];

    const float* h1 = ws + 3 * B_ * H_;  // h1buf[(T-1)&1] = h1buf[1]
    const int bb = blockIdx.x >> 5;
    const int cb = blockIdx.x & 31;
    const int tid = threadIdx.x;
    const int srow = tid >> 3;
    const int kv = tid & 7;
    const int wave = tid >> 6;
    const int lane = tid & 63;
    const int br = lane >> 3;
    const int gc8 = lane & 7;
    const int crow = cb * 32 + srow;

    float acc[4][4];
#pragma unroll
    for (int a = 0; a < 4; ++a)
#pragma unroll
        for (int b = 0; b < 4; ++b) acc[a][b] = 0.0f;

    for (int cc = 0; cc < 2; ++cc) {
        const float* ap = h1 + (bb * 32 + srow) * H_ + cc * 128;
#pragma unroll
        for (int i = 0; i < 4; ++i) {
            const int k4 = (kv + 8 * i) * 4;
            float4 va = *(const float4*)(ap + k4);
            As[(k4 + 0) * 36 + srow] = va.x;
            As[(k4 + 1) * 36 + srow] = va.y;
            As[(k4 + 2) * 36 + srow] = va.z;
            As[(k4 + 3) * 36 + srow] = va.w;
            float4 vw = make_float4(0.f, 0.f, 0.f, 0.f);
            if (crow < C_) vw = *(const float4*)(fcW + crow * H_ + cc * 128 + k4);
            Wsh[(k4 + 0) * 36 + srow] = vw.x;
            Wsh[(k4 + 1) * 36 + srow] = vw.y;
            Wsh[(k4 + 2) * 36 + srow] = vw.z;
            Wsh[(k4 + 3) * 36 + srow] = vw.w;
        }
        __syncthreads();
        const float* Ap = &As[(wave * 32) * 36 + br * 4];
        const float* Wp = &Wsh[(wave * 32) * 36 + gc8 * 4];
#pragma unroll
        for (int kk = 0; kk < 32; ++kk) {
            float4 a = *(const float4*)(Ap + kk * 36);
            float4 wv = *(const float4*)(Wp + kk * 36);
            acc[0][0] += a.x * wv.x; acc[0][1] += a.x * wv.y; acc[0][2] += a.x * wv.z; acc[0][3] += a.x * wv.w;
            acc[1][0] += a.y * wv.x; acc[1][1] += a.y * wv.y; acc[1][2] += a.y * wv.z; acc[1][3] += a.y * wv.w;
            acc[2][0] += a.z * wv.x; acc[2][1] += a.z * wv.y; acc[2][2] += a.z * wv.z; acc[2][3] += a.z * wv.w;
            acc[3][0] += a.w * wv.x; acc[3][1] += a.w * wv.y; acc[3][2] += a.w * wv.z; acc[3][3] += a.w * wv.w;
        }
        __syncthreads();
    }

    float* red = As;
    {
        const int base = tid * RSTR;
#pragma unroll
        for (int a = 0; a < 4; ++a)
#pragma unroll
            for (int b = 0; b < 4; ++b)
                red[base + a * 4 + b] = acc[a][b];
    }
    __syncthreads();
    {
        const int bl = tid >> 3;
        const int j = tid & 7;
#pragma unroll
        for (int g = 0; g < 4; ++g) {
            const int gc = g * 8 + j;
            const int br2 = bl >> 2, bi2 = bl & 3, gq = gc >> 2, gj = gc & 3;
            float v = 0.0f;
#pragma unroll
            for (int wv = 0; wv < 4; ++wv)
                v += red[(wv * 64 + br2 * 8 + gq) * RSTR + bi2 * 4 + gj];
            const int cglob = cb * 32 + gc;
            if (cglob < C_) {
                v += fcb[cglob];
                out[(size_t)(bb * 32 + bl) * C_ + cglob] = v;
            }
        }
    }
}

extern "C" void kernel_launch(void* const* d_in, const int* in_sizes, int n_in,
                              void* d_out, int out_size, void* d_ws, size_t ws_size,
                              hipStream_t stream)
{
    const float* x    = (const float*)d_in[0];
    const float* Wih0 = (const float*)d_in[1];
    const float* Whh0 = (const float*)d_in[2];
    const float* bih0 = (const float*)d_in[3];
    const float* bhh0 = (const float*)d_in[4];
    const float* Wih1 = (const float*)d_in[5];
    const float* Whh1 = (const float*)d_in[6];
    const float* bih1 = (const float*)d_in[7];
    const float* bhh1 = (const float*)d_in[8];
    const float* fcW  = (const float*)d_in[9];
    const float* fcb  = (const float*)d_in[10];
    float* ws  = (float*)d_ws;
    float* out = (float*)d_out;

    // zero h0[2], h1[2], c0, c1 (ws is re-poisoned before every call)
    hipMemsetAsync(d_ws, 0, (size_t)6 * B_ * H_ * sizeof(float), stream);

    // pipelined: launch s does L0 @ t=s and L1 @ t=s-1 (independent within launch)
    for (int s = 0; s <= T_; ++s) {
        lstm_step<<<512, 256, 0, stream>>>(x, Wih0, Whh0, bih0, bhh0,
                                           Wih1, Whh1, bih1, bhh1, ws, s);
    }
    fc_kernel<<<256, 256, 0, stream>>>(ws, fcW, fcb, out);
}